// Round 7
// baseline (9709.769 us; speedup 1.0000x reference)
//
#include <hip/hip_runtime.h>
#include <hip/hip_fp16.h>

typedef _Float16 f16x8 __attribute__((ext_vector_type(8)));
typedef float f32x4 __attribute__((ext_vector_type(4)));

namespace {
constexpr int BB = 32;    // batch
constexpr int SS = 512;   // seq len
constexpr int HH = 512;   // hidden
constexpr int G4 = 2048;  // 4*H gates
constexpr int FPAD = 16;  // flag padding: 16 ints = 64B line per flag
}

// ---------------- utility kernels ----------------
__global__ void k_zero(int* __restrict__ p, int n) {
  int i = blockIdx.x * blockDim.x + threadIdx.x;
  if (i < n) p[i] = 0;
}

__global__ void k_cvt(const float* __restrict__ s, _Float16* __restrict__ d, int n) {
  int i = blockIdx.x * blockDim.x + threadIdx.x;
  int stride = gridDim.x * blockDim.x;
  for (; i < n; i += stride) d[i] = (_Float16)s[i];
}

// permuting convert for Whh: out row' = unit*4 + gate (in row = gate*512 + unit),
// so a 16-row MFMA tile = 4 units x 4 gates and one lane's D-frag holds all 4
// gates of one (unit, batch) -> pointwise entirely in registers, zero LDS.
__global__ void k_cvtw(const float* __restrict__ s, _Float16* __restrict__ d) {
  int i = blockIdx.x * blockDim.x + threadIdx.x;
  int stride = gridDim.x * blockDim.x;
  for (; i < G4 * HH; i += stride) {
    const int row = i >> 9, k = i & 511;
    const int u = row >> 2, g = row & 3;
    d[i] = (_Float16)s[(size_t)(g * HH + u) * HH + k];
  }
}

// ---------------- input-projection GEMM (unchanged, proven) ----------------
__global__ __launch_bounds__(256) void k_gemm(
    const _Float16* __restrict__ Ain,  // [16384][K]
    const _Float16* __restrict__ W,    // [2][2048][K]
    const float* __restrict__ bih0, const float* __restrict__ bhh0,
    const float* __restrict__ bih1, const float* __restrict__ bhh1,
    _Float16* __restrict__ gx,         // [2][512][32][2048]
    int K) {
  __shared__ _Float16 As[128][40];
  __shared__ _Float16 Bs[128][40];
  const int tid = threadIdx.x;
  const int lane = tid & 63, wave = tid >> 6;
  const int dir = blockIdx.z;
  const int r0 = blockIdx.x * 128;
  const int n0 = blockIdx.y * 128;
  const _Float16* Wd = W + (size_t)dir * G4 * K;
  const float* bi = dir ? bih1 : bih0;
  const float* bh = dir ? bhh1 : bhh0;
  const int mw = wave & 1, nw = wave >> 1;

  f32x4 acc[4][4];
#pragma unroll
  for (int a = 0; a < 4; ++a)
#pragma unroll
    for (int b = 0; b < 4; ++b) acc[a][b] = (f32x4){0.f, 0.f, 0.f, 0.f};

  const int c1 = tid, c2 = tid + 256;
  const int ar1 = c1 >> 2, ak1 = (c1 & 3) * 8;
  const int ar2 = c2 >> 2, ak2 = (c2 & 3) * 8;
  const int fr = lane & 15, fq = (lane >> 4) * 8;

  const int nstage = K >> 5;
  for (int ks = 0; ks < nstage; ++ks) {
    const int k0 = ks << 5;
    *(f16x8*)&As[ar1][ak1] = *(const f16x8*)&Ain[(size_t)(r0 + ar1) * K + k0 + ak1];
    *(f16x8*)&As[ar2][ak2] = *(const f16x8*)&Ain[(size_t)(r0 + ar2) * K + k0 + ak2];
    *(f16x8*)&Bs[ar1][ak1] = *(const f16x8*)&Wd[(size_t)(n0 + ar1) * K + k0 + ak1];
    *(f16x8*)&Bs[ar2][ak2] = *(const f16x8*)&Wd[(size_t)(n0 + ar2) * K + k0 + ak2];
    __syncthreads();
    f16x8 af[4], bf[4];
#pragma unroll
    for (int mt = 0; mt < 4; ++mt) af[mt] = *(const f16x8*)&As[mw * 64 + mt * 16 + fr][fq];
#pragma unroll
    for (int nt = 0; nt < 4; ++nt) bf[nt] = *(const f16x8*)&Bs[nw * 64 + nt * 16 + fr][fq];
#pragma unroll
    for (int mt = 0; mt < 4; ++mt)
#pragma unroll
      for (int nt = 0; nt < 4; ++nt)
        acc[mt][nt] = __builtin_amdgcn_mfma_f32_16x16x32_f16(af[mt], bf[nt], acc[mt][nt], 0, 0, 0);
    __syncthreads();
  }

  const int q4 = (lane >> 4) * 4;
#pragma unroll
  for (int nt = 0; nt < 4; ++nt) {
    const int col = n0 + nw * 64 + nt * 16 + fr;
    const float bsum = bi[col] + bh[col];
#pragma unroll
    for (int mt = 0; mt < 4; ++mt) {
#pragma unroll
      for (int q = 0; q < 4; ++q) {
        const int r = r0 + mw * 64 + mt * 16 + q4 + q;
        const int b = r >> 9, t = r & 511;
        gx[(((size_t)dir * SS + t) * BB + b) * G4 + col] = (_Float16)(acc[mt][nt][q] + bsum);
      }
    }
  }
}

// ---------------- fast activations ----------------
__device__ __forceinline__ float sigmoid_fast(float x) {
  return __fdividef(1.f, 1.f + __expf(-x));
}
__device__ __forceinline__ float tanh_fast(float x) {
  const float e = __expf(2.f * x);
  return 1.f - __fdividef(2.f, e + 1.f);
}

// ---------------- recurrence R11: zero-LDS, R9-proven agent protocol ----------------
// 64 WGs x 512thr. Domain = (dir, batch-quarter) = 8 WGs (dom = blockIdx&7);
// rank ub = blockIdx>>3 owns units ub*64..+63 of the domain's 8 batches.
// Wave w owns 8 units (u0 = ub*64 + w*8), all 4 gates, FULL K=512: 2 full-K
// 16x16 tiles of unit-major-permuted Whh -> lane's 4 accs = 4 gates of one
// (unit, batch). No LDS at all: no partial scatter, no B2 barrier, no reduce.
// Exchange protocol byte-for-byte R9 (proven): agent-scope atomic quad stores,
// release fence + __syncthreads drain + tid0 agent flag; consumer lanes<8 poll
// 8 flag lines, __all, acquire fence, agent-scope bulk loads. Monotone flags,
// cooperative launch -> no deadlock. (R10's XCD-local fast path retired: it
// shipped an unbounded spin on unverified cache semantics and the container
// died; a bounded-fallback variant is the next experiment AFTER this lever is
// measured in isolation.)
__global__ __launch_bounds__(512, 1) void k_recur(
    const _Float16* __restrict__ gx,   // [2][512][32][2048]
    const _Float16* __restrict__ Wp,   // [2][2048][512] unit-major permuted, this layer
    _Float16* __restrict__ ex,         // [2][512][4][8][512] exchange
    _Float16* __restrict__ y,          // nullable [32][512][1024] fp16 canonical
    float* __restrict__ outf,          // nullable [32][512][1024] fp32 (layer 1)
    int* __restrict__ flags) {         // [8 doms][8 ranks][FPAD], this layer
  const int bx = blockIdx.x;
  const int tid = threadIdx.x;
  const int lane = tid & 63, wave = tid >> 6;
  const int dom = bx & 7, ub = bx >> 3;
  const int dir = dom & 1, bq = dom >> 1;
  const int c = lane & 15, qd = lane >> 4, cb = c & 7;
  const int u0 = ub * 64 + wave * 8;

  // weights: 2 full-K tiles, rows' = 4*u0 + 16*h2 + c, k = kj*32 + qd*8
  const _Float16* Wpd = Wp + (size_t)dir * G4 * HH;
  f16x8 af[2][16];
#pragma unroll
  for (int h2 = 0; h2 < 2; ++h2)
#pragma unroll
    for (int kj = 0; kj < 16; ++kj)
      af[h2][kj] =
          *(const f16x8*)&Wpd[(size_t)(4 * u0 + 16 * h2 + c) * HH + kj * 32 + qd * 8];

  const _Float16* gxd = gx + (size_t)dir * SS * BB * G4;
  _Float16* exd = ex + (size_t)dir * SS * 4 * 4096;
  int* fl = flags + dom * 8 * FPAD;
  float cst0 = 0.f, cst1 = 0.f;

  struct U2 { unsigned long long a, b; };

  for (int s = 0; s < SS; ++s) {
    const int t = dir ? (SS - 1 - s) : s;
    const int tprev = dir ? (t + 1) : (t - 1);

    // gx prefetch: gate g of units u0+qd (h2=0) / u0+4+qd (h2=1), batch bq*8+cb
    const _Float16* gq = gxd + ((size_t)t * BB + (bq * 8 + cb)) * G4 + u0 + qd;
    float gxv0[4], gxv1[4];
#pragma unroll
    for (int g = 0; g < 4; ++g) {
      gxv0[g] = (float)gq[g * HH];
      gxv1[g] = (float)gq[g * HH + 4];
    }

    f32x4 acc0 = {0.f, 0.f, 0.f, 0.f}, acc1 = {0.f, 0.f, 0.f, 0.f};

    if (s > 0) {
      // narrow poll: lanes 0..7 watch the domain's 8 producer flags (R4 shape)
      while (true) {
        int v = s;
        if (lane < 8)
          v = __hip_atomic_load(&fl[lane * FPAD], __ATOMIC_RELAXED, __HIP_MEMORY_SCOPE_AGENT);
        if (__all(v >= s)) break;
        __builtin_amdgcn_s_sleep(1);
      }
      __atomic_signal_fence(__ATOMIC_ACQUIRE);
      // B-frags: h(t-1)[batch cb][k = kj*32 + qd*8 .. +8]
      const _Float16* exr = exd + ((size_t)tprev * 4 + bq) * 4096 + cb * 512 + qd * 8;
#pragma unroll
      for (int kj = 0; kj < 16; ++kj) {
        const unsigned long long* p8 = (const unsigned long long*)&exr[kj * 32];
        U2 u;
        u.a = __hip_atomic_load(p8, __ATOMIC_RELAXED, __HIP_MEMORY_SCOPE_AGENT);
        u.b = __hip_atomic_load(p8 + 1, __ATOMIC_RELAXED, __HIP_MEMORY_SCOPE_AGENT);
        const f16x8 bf = __builtin_bit_cast(f16x8, u);
        acc0 = __builtin_amdgcn_mfma_f32_16x16x32_f16(af[0][kj], bf, acc0, 0, 0, 0);
        acc1 = __builtin_amdgcn_mfma_f32_16x16x32_f16(af[1][kj], bf, acc1, 0, 0, 0);
      }
    }
    // pointwise: lane holds all 4 gates of (unit u0+qd, batch cb) and (u0+4+qd, cb)
    const float i0 = sigmoid_fast(acc0[0] + gxv0[0]);
    const float f0 = sigmoid_fast(acc0[1] + gxv0[1]);
    const float g0 = tanh_fast(acc0[2] + gxv0[2]);
    const float o0 = sigmoid_fast(acc0[3] + gxv0[3]);
    cst0 = f0 * cst0 + i0 * g0;
    const float hv0 = o0 * tanh_fast(cst0);
    const float i1 = sigmoid_fast(acc1[0] + gxv1[0]);
    const float f1 = sigmoid_fast(acc1[1] + gxv1[1]);
    const float g1 = tanh_fast(acc1[2] + gxv1[2]);
    const float o1 = sigmoid_fast(acc1[3] + gxv1[3]);
    cst1 = f1 * cst1 + i1 * g1;
    const float hv1 = o1 * tanh_fast(cst1);

    // pack across qd (lanes c, c+16, c+32, c+48): quads units [u0..u0+3], [u0+4..u0+7]
    const unsigned hb0 = (unsigned)__builtin_bit_cast(unsigned short, (_Float16)hv0);
    const unsigned hb1 = (unsigned)__builtin_bit_cast(unsigned short, (_Float16)hv1);
    const unsigned p0 = hb0 | (__shfl_down(hb0, 16) << 16);
    const unsigned p1 = hb1 | (__shfl_down(hb1, 16) << 16);
    const unsigned long long qu0 =
        (unsigned long long)p0 | ((unsigned long long)__shfl_down(p0, 32) << 32);
    const unsigned long long qu1 =
        (unsigned long long)p1 | ((unsigned long long)__shfl_down(p1, 32) << 32);

    if (qd == 0 && c < 8) {
      unsigned long long* exw =
          (unsigned long long*)(exd + ((size_t)t * 4 + bq) * 4096 + c * 512 + u0);
      __hip_atomic_store(exw, qu0, __ATOMIC_RELAXED, __HIP_MEMORY_SCOPE_AGENT);
      __hip_atomic_store(exw + 1, qu1, __ATOMIC_RELAXED, __HIP_MEMORY_SCOPE_AGENT);
    }
    __atomic_signal_fence(__ATOMIC_RELEASE);
    __syncthreads();  // drain all waves' ex stores (vmcnt 0) before the signal
    if (tid == 0)
      __hip_atomic_store(&fl[ub * FPAD], s + 1, __ATOMIC_RELAXED, __HIP_MEMORY_SCOPE_AGENT);

    // off the critical path: canonical y (next-layer GEMM input) + fp32 out
    if (y && qd == 0 && c < 8) {
      unsigned long long* yw =
          (unsigned long long*)(y + ((size_t)(bq * 8 + c) * SS + t) * 1024 + dir * HH + u0);
      yw[0] = qu0;
      yw[1] = qu1;
    }
    if (outf && c < 8) {
      float* ob = outf + ((size_t)(bq * 8 + cb) * SS + t) * 1024 + dir * HH + u0 + qd;
      ob[0] = hv0;
      ob[4] = hv1;
    }
  }
}

// ---------------- launch ----------------
extern "C" void kernel_launch(void* const* d_in, const int* in_sizes, int n_in,
                              void* d_out, int out_size, void* d_ws, size_t ws_size,
                              hipStream_t stream) {
  (void)in_sizes; (void)n_in; (void)out_size; (void)ws_size;
  const float* x = (const float*)d_in[0];
  const float* Wih[4] = {(const float*)d_in[1], (const float*)d_in[5],
                         (const float*)d_in[9], (const float*)d_in[13]};
  const float* Whh[4] = {(const float*)d_in[2], (const float*)d_in[6],
                         (const float*)d_in[10], (const float*)d_in[14]};
  const float* bih[4] = {(const float*)d_in[3], (const float*)d_in[7],
                         (const float*)d_in[11], (const float*)d_in[15]};
  const float* bhh[4] = {(const float*)d_in[4], (const float*)d_in[8],
                         (const float*)d_in[12], (const float*)d_in[16]};

  char* p = (char*)d_ws;
  auto take = [&](size_t bytes) { char* r = p; p += (bytes + 255) & ~(size_t)255; return r; };
  _Float16* x16  = (_Float16*)take((size_t)BB * SS * 512 * 2);
  _Float16* wih0 = (_Float16*)take((size_t)2 * G4 * 512 * 2);
  _Float16* wih1 = (_Float16*)take((size_t)2 * G4 * 1024 * 2);
  _Float16* whhp = (_Float16*)take((size_t)4 * G4 * HH * 2);       // unit-major permuted
  _Float16* gx   = (_Float16*)take((size_t)2 * SS * BB * G4 * 2);
  _Float16* y0   = (_Float16*)take((size_t)BB * SS * 1024 * 2);
  _Float16* ex   = (_Float16*)take((size_t)2 * SS * 4 * 4096 * 2); // 32 MiB, reused by both layers
  int* flags     = (int*)take((size_t)2 * 8 * 8 * FPAD * 4);       // 2 layers x 8 doms x 8 ranks

  hipLaunchKernelGGL(k_zero, dim3(8), dim3(256), 0, stream, flags, 2 * 8 * 8 * FPAD);
  hipLaunchKernelGGL(k_cvt, dim3(512), dim3(256), 0, stream, x, x16, BB * SS * 512);
  hipLaunchKernelGGL(k_cvt, dim3(128), dim3(256), 0, stream, Wih[0], wih0, G4 * 512);
  hipLaunchKernelGGL(k_cvt, dim3(128), dim3(256), 0, stream, Wih[1], wih0 + (size_t)G4 * 512, G4 * 512);
  hipLaunchKernelGGL(k_cvt, dim3(256), dim3(256), 0, stream, Wih[2], wih1, G4 * 1024);
  hipLaunchKernelGGL(k_cvt, dim3(256), dim3(256), 0, stream, Wih[3], wih1 + (size_t)G4 * 1024, G4 * 1024);
  for (int i = 0; i < 4; ++i)
    hipLaunchKernelGGL(k_cvtw, dim3(512), dim3(256), 0, stream, Whh[i],
                       whhp + (size_t)i * G4 * HH);

  // layer 0
  hipLaunchKernelGGL(k_gemm, dim3(128, 16, 2), dim3(256), 0, stream,
                     x16, wih0, bih[0], bhh[0], bih[1], bhh[1], gx, 512);
  {
    const _Float16* gxp = gx; const _Float16* wpp = whhp;
    _Float16* exp_ = ex; _Float16* yp = y0; float* op = nullptr; int* cp = flags;
    void* args[] = {&gxp, &wpp, &exp_, &yp, &op, &cp};
    hipLaunchCooperativeKernel((const void*)k_recur, dim3(64), dim3(512), args, 0, stream);
  }
  // layer 1
  hipLaunchKernelGGL(k_gemm, dim3(128, 16, 2), dim3(256), 0, stream,
                     y0, wih1, bih[2], bhh[2], bih[3], bhh[3], gx, 1024);
  {
    const _Float16* gxp = gx; const _Float16* wpp = whhp + (size_t)2 * G4 * HH;
    _Float16* exp_ = ex; _Float16* yp = nullptr; float* op = (float*)d_out;
    int* cp = flags + 8 * 8 * FPAD;
    void* args[] = {&gxp, &wpp, &exp_, &yp, &op, &cp};
    hipLaunchCooperativeKernel((const void*)k_recur, dim3(64), dim3(512), args, 0, stream);
  }
}

// Round 8
// 4173.632 us; speedup vs baseline: 2.3265x; 2.3265x over previous
//
#include <hip/hip_runtime.h>
#include <hip/hip_fp16.h>

typedef _Float16 f16x8 __attribute__((ext_vector_type(8)));
typedef float f32x4 __attribute__((ext_vector_type(4)));

namespace {
constexpr int BB = 32;    // batch
constexpr int SS = 512;   // seq len
constexpr int HH = 512;   // hidden
constexpr int G4 = 2048;  // 4*H gates
constexpr int NWGR = 32;  // workgroups per direction in recurrence (512 thr each)
constexpr int FPAD = 16;  // flag padding: 16 ints = 64B line per flag
}

// ---------------- utility kernels ----------------
__global__ void k_zero(int* __restrict__ p, int n) {
  int i = blockIdx.x * blockDim.x + threadIdx.x;
  if (i < n) p[i] = 0;
}

__global__ void k_cvt(const float* __restrict__ s, _Float16* __restrict__ d, int n) {
  int i = blockIdx.x * blockDim.x + threadIdx.x;
  int stride = gridDim.x * blockDim.x;
  for (; i < n; i += stride) d[i] = (_Float16)s[i];
}

// ---------------- input-projection GEMM (unchanged, proven) ----------------
__global__ __launch_bounds__(256) void k_gemm(
    const _Float16* __restrict__ Ain,  // [16384][K]
    const _Float16* __restrict__ W,    // [2][2048][K]
    const float* __restrict__ bih0, const float* __restrict__ bhh0,
    const float* __restrict__ bih1, const float* __restrict__ bhh1,
    _Float16* __restrict__ gx,         // [2][512][32][2048]
    int K) {
  __shared__ _Float16 As[128][40];
  __shared__ _Float16 Bs[128][40];
  const int tid = threadIdx.x;
  const int lane = tid & 63, wave = tid >> 6;
  const int dir = blockIdx.z;
  const int r0 = blockIdx.x * 128;
  const int n0 = blockIdx.y * 128;
  const _Float16* Wd = W + (size_t)dir * G4 * K;
  const float* bi = dir ? bih1 : bih0;
  const float* bh = dir ? bhh1 : bhh0;
  const int mw = wave & 1, nw = wave >> 1;

  f32x4 acc[4][4];
#pragma unroll
  for (int a = 0; a < 4; ++a)
#pragma unroll
    for (int b = 0; b < 4; ++b) acc[a][b] = (f32x4){0.f, 0.f, 0.f, 0.f};

  const int c1 = tid, c2 = tid + 256;
  const int ar1 = c1 >> 2, ak1 = (c1 & 3) * 8;
  const int ar2 = c2 >> 2, ak2 = (c2 & 3) * 8;
  const int fr = lane & 15, fq = (lane >> 4) * 8;

  const int nstage = K >> 5;
  for (int ks = 0; ks < nstage; ++ks) {
    const int k0 = ks << 5;
    *(f16x8*)&As[ar1][ak1] = *(const f16x8*)&Ain[(size_t)(r0 + ar1) * K + k0 + ak1];
    *(f16x8*)&As[ar2][ak2] = *(const f16x8*)&Ain[(size_t)(r0 + ar2) * K + k0 + ak2];
    *(f16x8*)&Bs[ar1][ak1] = *(const f16x8*)&Wd[(size_t)(n0 + ar1) * K + k0 + ak1];
    *(f16x8*)&Bs[ar2][ak2] = *(const f16x8*)&Wd[(size_t)(n0 + ar2) * K + k0 + ak2];
    __syncthreads();
    f16x8 af[4], bf[4];
#pragma unroll
    for (int mt = 0; mt < 4; ++mt) af[mt] = *(const f16x8*)&As[mw * 64 + mt * 16 + fr][fq];
#pragma unroll
    for (int nt = 0; nt < 4; ++nt) bf[nt] = *(const f16x8*)&Bs[nw * 64 + nt * 16 + fr][fq];
#pragma unroll
    for (int mt = 0; mt < 4; ++mt)
#pragma unroll
      for (int nt = 0; nt < 4; ++nt)
        acc[mt][nt] = __builtin_amdgcn_mfma_f32_16x16x32_f16(af[mt], bf[nt], acc[mt][nt], 0, 0, 0);
    __syncthreads();
  }

  const int q4 = (lane >> 4) * 4;
#pragma unroll
  for (int nt = 0; nt < 4; ++nt) {
    const int col = n0 + nw * 64 + nt * 16 + fr;
    const float bsum = bi[col] + bh[col];
#pragma unroll
    for (int mt = 0; mt < 4; ++mt) {
#pragma unroll
      for (int q = 0; q < 4; ++q) {
        const int r = r0 + mw * 64 + mt * 16 + q4 + q;
        const int b = r >> 9, t = r & 511;
        gx[(((size_t)dir * SS + t) * BB + b) * G4 + col] = (_Float16)(acc[mt][nt][q] + bsum);
      }
    }
  }
}

// ---------------- fast activations ----------------
__device__ __forceinline__ float sigmoid_fast(float x) {
  return __fdividef(1.f, 1.f + __expf(-x));
}
__device__ __forceinline__ float tanh_fast(float x) {
  const float e = __expf(2.f * x);
  return 1.f - __fdividef(2.f, e + 1.f);
}

// ---------------- recurrence: 64 WGs = 32 x 512thr per direction ----------------
// R12 = the proven R4 kernel (1841us/dispatch) with ONE change: the global
// flag poll is executed by a single wave per kc (m==0); its kc-partner wave
// (m==1) spins on a CU-local LDS word instead. This cuts pollers per flag
// line 8x (256 -> 32 waves): the poll storm was inflating the detect RT via
// LLC same-line queuing. Protocol, partition, LDS layout, barriers, signal,
// and write placement are byte-for-byte R4. Bounded downside: partner pays
// ~200cy LDS hop; release/acquire chain unchanged (producer drains h before
// flag; poller detect happens-before the LDS bump; partner h-loads are
// agent-scope -> read LLC).
__global__ __launch_bounds__(512, 1) void k_recur(
    const _Float16* __restrict__ gx,   // [2][512][32][2048]
    const _Float16* __restrict__ Whh,  // [2][2048][512] fp16, this layer
    _Float16* __restrict__ y,          // [32][512][1024] fp16 layer output
    float* __restrict__ outf,          // nullptr, or [32][512][1024] fp32 (layer 1)
    int* __restrict__ flags) {         // [2][NWGR*FPAD]
  const int tid = threadIdx.x;
  const int lane = tid & 63, wave = tid >> 6;   // wave 0..7
  const int wg = blockIdx.x & (NWGR - 1);
  const int dir = blockIdx.x >> 5;
  const int m = wave & 1, kc = wave >> 1;       // batch half, K chunk

  __shared__ float gp_s[16][32][18];            // [kc*4+gate][batch][unit] partials
  __shared__ int done_s[4];                     // per-kc detected step (LDS broadcast)

  const int c = lane & 15;
  const int qd = lane >> 4;
  const int quad8 = qd * 8;

  // B-frags: gate row = g*512 + wg*16 + c, k = kc*128 + kj*32 + quad8
  const _Float16* WdB = Whh + (size_t)dir * G4 * HH;
  f16x8 bfrag[4][4];
#pragma unroll
  for (int g = 0; g < 4; ++g)
#pragma unroll
    for (int kj = 0; kj < 4; ++kj)
      bfrag[g][kj] =
          *(const f16x8*)&WdB[(size_t)(g * HH + wg * 16 + c) * HH + kc * 128 + kj * 32 + quad8];

  const int tb = tid >> 4, tu = tid & 15;  // pointwise ownership (batch, unit)
  float cstate = 0.f;

  const _Float16* gxd = gx + (size_t)dir * SS * BB * G4;
  int* fl = flags + dir * (NWGR * FPAD);
  // this wave's K-chunk [kc*128, kc*128+128) is produced by WGs kc*8 .. kc*8+7
  const int myprod = kc * 8 + (lane & 7);

  if (tid < 4) done_s[tid] = 0;
  __syncthreads();

  struct U2 { unsigned long long a, b; };

  for (int s = 0; s < SS; ++s) {
    const int t = dir ? (SS - 1 - s) : s;
    const int tprev = dir ? (t + 1) : (t - 1);

    // gx prefetch (plain cached loads; overlaps the wait)
    const _Float16* gq = gxd + ((size_t)t * BB + tb) * G4 + wg * 16 + tu;
    const float gxi = (float)gq[0];
    const float gxf = (float)gq[HH];
    const float gxg = (float)gq[2 * HH];
    const float gxo = (float)gq[3 * HH];

    f32x4 acc[4];
#pragma unroll
    for (int g = 0; g < 4; ++g) acc[g] = (f32x4){0.f, 0.f, 0.f, 0.f};

    if (s > 0) {
      if (m == 0) {
        // poller wave for this kc: lanes 0..7 each watch one of the 8 producers
        while (true) {
          int v = s;
          if (lane < 8)
            v = __hip_atomic_load(&fl[myprod * FPAD], __ATOMIC_RELAXED, __HIP_MEMORY_SCOPE_AGENT);
          if (__all(v >= s)) break;
          __builtin_amdgcn_s_sleep(1);
        }
        __atomic_signal_fence(__ATOMIC_ACQUIRE);
        if (lane == 0)
          __hip_atomic_store(&done_s[kc], s, __ATOMIC_RELAXED, __HIP_MEMORY_SCOPE_WORKGROUP);
      } else {
        // partner wave: CU-local LDS spin (no fabric traffic)
        while (__hip_atomic_load(&done_s[kc], __ATOMIC_RELAXED, __HIP_MEMORY_SCOPE_WORKGROUP) < s)
          __builtin_amdgcn_s_sleep(1);
        __atomic_signal_fence(__ATOMIC_ACQUIRE);
      }
      // A-frags: batch row = m*16 + c, this wave's disjoint 128-wide K chunk
      const _Float16* hrow = y + ((size_t)(m * 16 + c) * SS + tprev) * 1024 + dir * HH;
      const unsigned long long* h64 = (const unsigned long long*)hrow;
      f16x8 af[4];
#pragma unroll
      for (int kj = 0; kj < 4; ++kj) {
        const int o = kc * 32 + kj * 8 + qd * 2;
        U2 u;
        u.a = __hip_atomic_load(h64 + o, __ATOMIC_RELAXED, __HIP_MEMORY_SCOPE_AGENT);
        u.b = __hip_atomic_load(h64 + o + 1, __ATOMIC_RELAXED, __HIP_MEMORY_SCOPE_AGENT);
        af[kj] = __builtin_bit_cast(f16x8, u);
      }
#pragma unroll
      for (int kj = 0; kj < 4; ++kj)
#pragma unroll
        for (int g = 0; g < 4; ++g)
          acc[g] = __builtin_amdgcn_mfma_f32_16x16x32_f16(af[kj], bfrag[g][kj], acc[g], 0, 0, 0);
    }
    // scatter partials: D col = lane&15 (unit), row = qd*4+q (batch)
#pragma unroll
    for (int g = 0; g < 4; ++g)
#pragma unroll
      for (int q = 0; q < 4; ++q) gp_s[kc * 4 + g][m * 16 + qd * 4 + q][c] = acc[g][q];
    __syncthreads();  // B2: all waves' partials in LDS

    // pointwise: thread (tb, tu) reduces 4 K-chunk partials per gate
    const float ip = gp_s[0][tb][tu] + gp_s[4][tb][tu] + gp_s[8][tb][tu] + gp_s[12][tb][tu] + gxi;
    const float fp = gp_s[1][tb][tu] + gp_s[5][tb][tu] + gp_s[9][tb][tu] + gp_s[13][tb][tu] + gxf;
    const float gp = gp_s[2][tb][tu] + gp_s[6][tb][tu] + gp_s[10][tb][tu] + gp_s[14][tb][tu] + gxg;
    const float op = gp_s[3][tb][tu] + gp_s[7][tb][tu] + gp_s[11][tb][tu] + gp_s[15][tb][tu] + gxo;
    const float iv = sigmoid_fast(ip);
    const float fv = sigmoid_fast(fp);
    const float gv = tanh_fast(gp);
    const float ov = sigmoid_fast(op);
    cstate = fv * cstate + iv * gv;
    const float hv = ov * tanh_fast(cstate);

    // pack 4 lanes' fp16 h into one 8B value via shuffles (no LDS round trip).
    // lanes l..l+3 (l%4==0) hold units tu..tu+3 of batch tb (16 | 4: no straddle).
    const unsigned hb = (unsigned)__builtin_bit_cast(unsigned short, (_Float16)hv);
    const unsigned pair = hb | (__shfl_down(hb, 1) << 16);
    const unsigned long long quad =
        (unsigned long long)pair | ((unsigned long long)__shfl_down(pair, 2) << 32);
    if ((lane & 3) == 0) {
      unsigned long long* dst =
          (unsigned long long*)(y + ((size_t)tb * SS + t) * 1024 + dir * HH + wg * 16 + tu);
      __hip_atomic_store(dst, quad, __ATOMIC_RELAXED, __HIP_MEMORY_SCOPE_AGENT);
    }
    __atomic_signal_fence(__ATOMIC_RELEASE);
    __syncthreads();  // B4: every wave's h stores vmcnt-drained before the signal
    if (tid == 0)
      __hip_atomic_store(&fl[wg * FPAD], s + 1, __ATOMIC_RELAXED, __HIP_MEMORY_SCOPE_AGENT);
    // fp32 layer-1 output: after the signal, off the critical path
    if (outf) outf[((size_t)tb * SS + t) * 1024 + dir * HH + wg * 16 + tu] = hv;
  }
}

// ---------------- launch ----------------
extern "C" void kernel_launch(void* const* d_in, const int* in_sizes, int n_in,
                              void* d_out, int out_size, void* d_ws, size_t ws_size,
                              hipStream_t stream) {
  (void)in_sizes; (void)n_in; (void)out_size; (void)ws_size;
  const float* x = (const float*)d_in[0];
  const float* Wih[4] = {(const float*)d_in[1], (const float*)d_in[5],
                         (const float*)d_in[9], (const float*)d_in[13]};
  const float* Whh[4] = {(const float*)d_in[2], (const float*)d_in[6],
                         (const float*)d_in[10], (const float*)d_in[14]};
  const float* bih[4] = {(const float*)d_in[3], (const float*)d_in[7],
                         (const float*)d_in[11], (const float*)d_in[15]};
  const float* bhh[4] = {(const float*)d_in[4], (const float*)d_in[8],
                         (const float*)d_in[12], (const float*)d_in[16]};

  char* p = (char*)d_ws;
  auto take = [&](size_t bytes) { char* r = p; p += (bytes + 255) & ~(size_t)255; return r; };
  _Float16* x16  = (_Float16*)take((size_t)BB * SS * 512 * 2);
  _Float16* wih0 = (_Float16*)take((size_t)2 * G4 * 512 * 2);
  _Float16* wih1 = (_Float16*)take((size_t)2 * G4 * 1024 * 2);
  _Float16* whh16 = (_Float16*)take((size_t)4 * G4 * 512 * 2);
  _Float16* gx   = (_Float16*)take((size_t)2 * SS * BB * G4 * 2);
  _Float16* y0   = (_Float16*)take((size_t)BB * SS * 1024 * 2);
  _Float16* y1   = (_Float16*)take((size_t)BB * SS * 1024 * 2);
  int* flags     = (int*)take((size_t)2 * 2 * NWGR * FPAD * 4);  // 2 layers x 2 dirs

  hipLaunchKernelGGL(k_zero, dim3(8), dim3(256), 0, stream, flags, 2 * 2 * NWGR * FPAD);
  hipLaunchKernelGGL(k_cvt, dim3(512), dim3(256), 0, stream, x, x16, BB * SS * 512);
  hipLaunchKernelGGL(k_cvt, dim3(128), dim3(256), 0, stream, Wih[0], wih0, G4 * 512);
  hipLaunchKernelGGL(k_cvt, dim3(128), dim3(256), 0, stream, Wih[1], wih0 + (size_t)G4 * 512, G4 * 512);
  hipLaunchKernelGGL(k_cvt, dim3(256), dim3(256), 0, stream, Wih[2], wih1, G4 * 1024);
  hipLaunchKernelGGL(k_cvt, dim3(256), dim3(256), 0, stream, Wih[3], wih1 + (size_t)G4 * 1024, G4 * 1024);
  for (int i = 0; i < 4; ++i)
    hipLaunchKernelGGL(k_cvt, dim3(128), dim3(256), 0, stream, Whh[i],
                       whh16 + (size_t)i * G4 * 512, G4 * 512);

  // layer 0
  hipLaunchKernelGGL(k_gemm, dim3(128, 16, 2), dim3(256), 0, stream,
                     x16, wih0, bih[0], bhh[0], bih[1], bhh[1], gx, 512);
  {
    const _Float16* gxp = gx; const _Float16* whhp = whh16;
    _Float16* yp = y0; float* op = nullptr; int* cp = flags;
    void* args[] = {&gxp, &whhp, &yp, &op, &cp};
    hipLaunchCooperativeKernel((const void*)k_recur, dim3(2 * NWGR), dim3(512), args, 0, stream);
  }
  // layer 1
  hipLaunchKernelGGL(k_gemm, dim3(128, 16, 2), dim3(256), 0, stream,
                     y0, wih1, bih[2], bhh[2], bih[3], bhh[3], gx, 1024);
  {
    const _Float16* gxp = gx; const _Float16* whhp = whh16 + (size_t)2 * G4 * 512;
    _Float16* yp = y1; float* op = (float*)d_out; int* cp = flags + 2 * NWGR * FPAD;
    void* args[] = {&gxp, &whhp, &yp, &op, &cp};
    hipLaunchCooperativeKernel((const void*)k_recur, dim3(2 * NWGR), dim3(512), args, 0, stream);
  }
}